// Round 3
// baseline (1225.943 us; speedup 1.0000x reference)
//
#include <hip/hip_runtime.h>

#define AS1 __attribute__((address_space(1)))
#define AS3 __attribute__((address_space(3)))

typedef __bf16 bf16x8 __attribute__((ext_vector_type(8)));
typedef float f32x4 __attribute__((ext_vector_type(4)));

// ---------- small helpers ----------
__device__ __forceinline__ unsigned short f2bf(float f) {
  unsigned u = __float_as_uint(f);
  u += 0x7FFFu + ((u >> 16) & 1u);   // RNE
  return (unsigned short)(u >> 16);
}
__device__ __forceinline__ float bf2f(unsigned short u) {
  return __uint_as_float(((unsigned)u) << 16);
}

__device__ __forceinline__ void gl_lds16(const void* g, void* l) {
  // async global->LDS, 16B per lane; LDS dest = wave-uniform base + lane*16
  // (global SOURCE address is per-lane — only the dest is lane-linear)
  __builtin_amdgcn_global_load_lds((const AS1 unsigned int*)g,
                                   (AS3 unsigned int*)l, 16, 0, 0);
}

// ---------- Threefry-2x32 (20 rounds), JAX-compatible ----------
__device__ __forceinline__ unsigned rotl32(unsigned v, int s) {
  return (v << s) | (v >> (32 - s));
}
__device__ __forceinline__ void threefry2x32(unsigned k0, unsigned k1,
                                             unsigned x0, unsigned x1,
                                             unsigned& o0, unsigned& o1) {
  const unsigned ks2 = k0 ^ k1 ^ 0x1BD11BDAu;
  x0 += k0; x1 += k1;
  x0 += x1; x1 = rotl32(x1, 13); x1 ^= x0;
  x0 += x1; x1 = rotl32(x1, 15); x1 ^= x0;
  x0 += x1; x1 = rotl32(x1, 26); x1 ^= x0;
  x0 += x1; x1 = rotl32(x1, 6);  x1 ^= x0;
  x0 += k1; x1 += ks2 + 1u;
  x0 += x1; x1 = rotl32(x1, 17); x1 ^= x0;
  x0 += x1; x1 = rotl32(x1, 29); x1 ^= x0;
  x0 += x1; x1 = rotl32(x1, 16); x1 ^= x0;
  x0 += x1; x1 = rotl32(x1, 24); x1 ^= x0;
  x0 += ks2; x1 += k0 + 2u;
  x0 += x1; x1 = rotl32(x1, 13); x1 ^= x0;
  x0 += x1; x1 = rotl32(x1, 15); x1 ^= x0;
  x0 += x1; x1 = rotl32(x1, 26); x1 ^= x0;
  x0 += x1; x1 = rotl32(x1, 6);  x1 ^= x0;
  x0 += k0; x1 += k1 + 3u;
  x0 += x1; x1 = rotl32(x1, 17); x1 ^= x0;
  x0 += x1; x1 = rotl32(x1, 29); x1 ^= x0;
  x0 += x1; x1 = rotl32(x1, 16); x1 ^= x0;
  x0 += x1; x1 = rotl32(x1, 24); x1 ^= x0;
  x0 += k1; x1 += ks2 + 4u;
  x0 += x1; x1 = rotl32(x1, 13); x1 ^= x0;
  x0 += x1; x1 = rotl32(x1, 15); x1 ^= x0;
  x0 += x1; x1 = rotl32(x1, 26); x1 ^= x0;
  x0 += x1; x1 = rotl32(x1, 6);  x1 ^= x0;
  o0 = x0 + ks2; o1 = x1 + k0 + 5u;
}

// XLA f32 erf_inv (Giles polynomial)
__device__ __forceinline__ float erfinv32(float x) {
  float w = -log1pf(-x * x);
  float p;
  if (w < 5.f) {
    w = w - 2.5f;
    p = 2.81022636e-08f;
    p = fmaf(p, w, 3.43273939e-07f);
    p = fmaf(p, w, -3.5233877e-06f);
    p = fmaf(p, w, -4.39150654e-06f);
    p = fmaf(p, w, 0.00021858087f);
    p = fmaf(p, w, -0.00125372503f);
    p = fmaf(p, w, -0.00417768164f);
    p = fmaf(p, w, 0.246640727f);
    p = fmaf(p, w, 1.50140941f);
  } else {
    w = sqrtf(w) - 3.f;
    p = -0.000200214257f;
    p = fmaf(p, w, 0.000100950558f);
    p = fmaf(p, w, 0.00134934322f);
    p = fmaf(p, w, -0.00367342844f);
    p = fmaf(p, w, 0.00573950773f);
    p = fmaf(p, w, -0.0076224613f);
    p = fmaf(p, w, 0.00943887047f);
    p = fmaf(p, w, 1.00167406f);
    p = fmaf(p, w, 2.83297682f);
  }
  return p * x;
}

// bits -> N(0,1) exactly as jax.random.normal (f32)
__device__ __forceinline__ float bits_to_normal(unsigned bits) {
  float f = __uint_as_float((bits >> 9) | 0x3f800000u) - 1.0f;  // [0,1)
  const float lo = -0.99999994f;
  float u = fmaf(f, 2.0f, lo);
  u = fmaxf(u, lo);
  return 1.41421356f * erfinv32(u);
}

// ---------- conversion / transpose kernels ----------
__global__ __launch_bounds__(256) void cvt_x(const float* __restrict__ in,
                                             unsigned short* __restrict__ out) {
  const int i = blockIdx.x * 256 + threadIdx.x;
  const float4 v = ((const float4*)in)[i];
  ushort4 o;
  o.x = f2bf(v.x); o.y = f2bf(v.y); o.z = f2bf(v.z); o.w = f2bf(v.w);
  ((ushort4*)out)[i] = o;
}

// in: [batch][R][C] f32  ->  out: [batch][C][R] bf16
__global__ __launch_bounds__(256) void transpose_bf16(
    const float* __restrict__ in, unsigned short* __restrict__ out, int R, int C) {
  __shared__ float tile[32][33];
  const int bz = blockIdx.z;
  in  += (size_t)bz * R * C;
  out += (size_t)bz * R * C;
  const int c0 = blockIdx.x * 32, r0 = blockIdx.y * 32;
  const int tx = threadIdx.x & 31, ty = threadIdx.x >> 5;  // 32x8
#pragma unroll
  for (int i = 0; i < 32; i += 8)
    tile[ty + i][tx] = in[(size_t)(r0 + ty + i) * C + c0 + tx];
  __syncthreads();
#pragma unroll
  for (int i = 0; i < 32; i += 8)
    out[(size_t)(c0 + ty + i) * R + r0 + tx] = f2bf(tile[tx][ty + i]);
}

// ---------- gating: mean/std/noise/top-k/softmax, all fp32 ----------
__global__ __launch_bounds__(256) void gating_kernel(
    const float* __restrict__ x, const float* __restrict__ Wg,
    const float* __restrict__ Wn, float* __restrict__ g) {
  __shared__ float xs[8][1024];
  __shared__ float partial[64][4][8];
  __shared__ float meanS[2][8][16];
  __shared__ float stdS[2][8][16];
  __shared__ float noisyS[2][8][16];
  const int tid = threadIdx.x;
  const int b0 = blockIdx.x * 8;
  for (int idx = tid; idx < 8 * 1024; idx += 256) {
    int r = idx >> 10, c = idx & 1023;
    xs[r][c] = x[(size_t)(b0 + r) * 1024 + c];
  }
  __syncthreads();
  {
    const int c = tid & 63;          // column id: t*32 + which*16 + e
    const int q = tid >> 6;          // K-partition 0..3
    const int t = c >> 5, which = (c >> 4) & 1, e = c & 15;
    const float* Wcol = (which ? Wn : Wg) + (size_t)t * 1024 * 16 + e;
    float acc[8] = {0, 0, 0, 0, 0, 0, 0, 0};
    const int i0 = q * 256;
    for (int i = i0; i < i0 + 256; ++i) {
      float w = Wcol[(size_t)i * 16];
#pragma unroll
      for (int r = 0; r < 8; ++r) acc[r] = fmaf(w, xs[r][i], acc[r]);
    }
#pragma unroll
    for (int r = 0; r < 8; ++r) partial[c][q][r] = acc[r];
  }
  __syncthreads();
  for (int idx = tid; idx < 512; idx += 256) {
    int c = idx >> 3, r = idx & 7;
    float s = partial[c][0][r] + partial[c][1][r] + partial[c][2][r] + partial[c][3][r];
    int t = c >> 5, which = (c >> 4) & 1, e = c & 15;
    if (which)  // softplus
      stdS[t][r][e] = fmaxf(s, 0.f) + log1pf(expf(-fabsf(s)));
    else
      meanS[t][r][e] = s;
  }
  __syncthreads();
  if (tid < 128) {
    int r = tid >> 4, e = tid & 15;
    unsigned p = (unsigned)((b0 + r) * 16 + e);
#pragma unroll
    for (int t = 0; t < 2; ++t) {
      unsigned n = (unsigned)t * 131072u + p;  // flat index into (T,B,E)
      unsigned y0, y1;
      threefry2x32(0u, 42u, 0u, n, y0, y1);    // partitionable: counter=(0, n)
      float nrm = bits_to_normal(y0 ^ y1);
      noisyS[t][r][e] = meanS[t][r][e] + nrm * stdS[t][r][e];
    }
  }
  __syncthreads();
  if (tid < 16) {
    int r = tid >> 1, t = tid & 1;
    float v[16];
#pragma unroll
    for (int e = 0; e < 16; ++e) v[e] = noisyS[t][r][e];
    float m0 = -1e30f, m1 = -1e30f, m2 = -1e30f, m3 = -1e30f;
#pragma unroll
    for (int e = 0; e < 16; ++e) {
      float val = v[e];
      if (val > m0) { m3 = m2; m2 = m1; m1 = m0; m0 = val; }
      else if (val > m1) { m3 = m2; m2 = m1; m1 = val; }
      else if (val > m2) { m3 = m2; m2 = val; }
      else if (val > m3) { m3 = val; }
    }
    float sum = 0.f, ge[16];
#pragma unroll
    for (int e = 0; e < 16; ++e) {
      if (v[e] >= m3) { ge[e] = expf(v[e] - m0); sum += ge[e]; }
      else ge[e] = 0.f;
    }
    float inv = 1.f / sum;
    float* grow = g + ((size_t)t * 8192 + (b0 + r)) * 16;
#pragma unroll
    for (int e = 0; e < 16; ++e) grow[e] = ge[e] * inv;
  }
}

// ---------- routing lists: per expert, rows used by either task ----------
__global__ __launch_bounds__(256) void build_routing(
    const float* __restrict__ g, int* __restrict__ count,
    int* __restrict__ rowlist, int* __restrict__ pos, int b0, int Bc) {
  const int bl = blockIdx.x * 256 + threadIdx.x;
  if (bl >= Bc) return;
  const int b = b0 + bl;
  const float* g0 = g + (size_t)b * 16;
  const float* g1 = g + (size_t)(8192 + b) * 16;
#pragma unroll
  for (int e = 0; e < 16; ++e) {
    if (g0[e] > 0.f || g1[e] > 0.f) {
      int i = atomicAdd(&count[e], 1);
      rowlist[e * Bc + i] = bl;
      pos[e * Bc + bl] = i;
    }
  }
}

// ---------- bf16 MFMA GEMM: C[M,N] = A[M,K] @ Bt[N,K]^T (+bias, opt relu) ----------
// Fragment-order LDS: each 16x32 sub-tile stored so lane L's MFMA fragment is
// at subtile_base + L*16B -> ds_read_b128 conflict-free (write side stays
// lane-linear as global_load_lds requires; we permute the GLOBAL source).
template <bool RELU, bool OUT_BF16>
__global__ __launch_bounds__(256) void gemm_bt(
    const unsigned short* __restrict__ A, int lda, long long strideA,
    const unsigned short* __restrict__ Bt, int ldb, long long strideB,
    void* __restrict__ Cv, int ldc, long long strideC,
    const float* __restrict__ bias, int strideBias, int K,
    const int* __restrict__ count) {
  __shared__ __align__(16) unsigned short As[8 * 512];
  __shared__ __align__(16) unsigned short Bs[8 * 512];
  const int tid = threadIdx.x;
  const int w = tid >> 6, lane = tid & 63;
  const int wm = w >> 1, wn = w & 1;
  const int bm = blockIdx.x, bn = blockIdx.y, bz = blockIdx.z;
  if (count && bm * 128 >= count[bz]) return;   // sparse early-exit

  const unsigned short* Ab = A + (size_t)bz * strideA + (size_t)bm * 128 * lda;
  const unsigned short* Bb = Bt + (size_t)bz * strideB + (size_t)bn * 128 * ldb;

  const int sr = lane & 15;          // row within 16-row sub-tile
  const int sc = (lane >> 4) * 8;    // k-chunk (8 bf16 = 16B)
  const unsigned short* gA0 = Ab + (size_t)(w * 32 + sr) * lda + sc;
  const unsigned short* gA1 = gA0 + (size_t)16 * lda;
  const unsigned short* gB0 = Bb + (size_t)(w * 32 + sr) * ldb + sc;
  const unsigned short* gB1 = gB0 + (size_t)16 * ldb;
  unsigned short* lA0 = &As[(w * 2) * 512];
  unsigned short* lA1 = &As[(w * 2 + 1) * 512];
  unsigned short* lB0 = &Bs[(w * 2) * 512];
  unsigned short* lB1 = &Bs[(w * 2 + 1) * 512];

  f32x4 acc[4][4] = {};

  for (int k0 = 0; k0 < K; k0 += 32) {
    __syncthreads();
    gl_lds16(gA0 + k0, lA0);
    gl_lds16(gA1 + k0, lA1);
    gl_lds16(gB0 + k0, lB0);
    gl_lds16(gB1 + k0, lB1);
    __syncthreads();
    bf16x8 af[4], bfr[4];
#pragma unroll
    for (int mt = 0; mt < 4; ++mt)
      af[mt] = *(const bf16x8*)&As[(wm * 4 + mt) * 512 + lane * 8];
#pragma unroll
    for (int nt = 0; nt < 4; ++nt)
      bfr[nt] = *(const bf16x8*)&Bs[(wn * 4 + nt) * 512 + lane * 8];
#pragma unroll
    for (int mt = 0; mt < 4; ++mt)
#pragma unroll
      for (int nt = 0; nt < 4; ++nt)
        acc[mt][nt] = __builtin_amdgcn_mfma_f32_16x16x32_bf16(
            af[mt], bfr[nt], acc[mt][nt], 0, 0, 0);
  }

  // epilogue: C/D layout col=lane&15, row=(lane>>4)*4+r (m89-verified)
  const int crow = (lane >> 4) * 4;
  const int ccol = lane & 15;
  const float* brow = bias + (size_t)bz * strideBias + (size_t)bn * 128;
#pragma unroll
  for (int nt = 0; nt < 4; ++nt) {
    int col = wn * 64 + nt * 16 + ccol;
    float bv = brow[col];
#pragma unroll
    for (int mt = 0; mt < 4; ++mt) {
      f32x4 v = acc[mt][nt];
#pragma unroll
      for (int r = 0; r < 4; ++r) {
        float val = v[r] + bv;
        if (RELU) val = fmaxf(val, 0.f);
        size_t row = (size_t)bm * 128 + wm * 64 + mt * 16 + crow + r;
        size_t off = (size_t)bz * strideC + row * ldc + (size_t)bn * 128 + col;
        if (OUT_BF16) ((unsigned short*)Cv)[off] = f2bf(val);
        else          ((float*)Cv)[off] = val;
      }
    }
  }
}

// ---------- FC1 with row gather: h[e][i][:] = relu(x[rowlist[e][i]] @ We1[e]) ----------
__global__ __launch_bounds__(256) void gemm_gather(
    const unsigned short* __restrict__ A, int lda,          // xb dense [8192][K]
    const unsigned short* __restrict__ Bt, int ldb, long long strideB,
    unsigned short* __restrict__ C, int ldc, long long strideC,
    const float* __restrict__ bias, int strideBias, int K,
    const int* __restrict__ rowlist, const int* __restrict__ count,
    int b0, int Bc) {
  __shared__ __align__(16) unsigned short As[8 * 512];
  __shared__ __align__(16) unsigned short Bs[8 * 512];
  const int tid = threadIdx.x;
  const int w = tid >> 6, lane = tid & 63;
  const int wm = w >> 1, wn = w & 1;
  const int bm = blockIdx.x, bn = blockIdx.y, e = blockIdx.z;
  const int cnt = count[e];
  if (bm * 128 >= cnt) return;

  const int sr = lane & 15;
  const int sc = (lane >> 4) * 8;
  // gather A rows via rowlist (per-lane global source is legal)
  const int i0 = bm * 128 + w * 32 + sr;
  const int i1 = i0 + 16;
  const int* rl = rowlist + (size_t)e * Bc;
  const int r0 = (i0 < cnt) ? rl[i0] : rl[0];
  const int r1 = (i1 < cnt) ? rl[i1] : rl[0];
  const unsigned short* gA0 = A + (size_t)(b0 + r0) * lda + sc;
  const unsigned short* gA1 = A + (size_t)(b0 + r1) * lda + sc;
  const unsigned short* Bb = Bt + (size_t)e * strideB + (size_t)bn * 128 * ldb;
  const unsigned short* gB0 = Bb + (size_t)(w * 32 + sr) * ldb + sc;
  const unsigned short* gB1 = gB0 + (size_t)16 * ldb;
  unsigned short* lA0 = &As[(w * 2) * 512];
  unsigned short* lA1 = &As[(w * 2 + 1) * 512];
  unsigned short* lB0 = &Bs[(w * 2) * 512];
  unsigned short* lB1 = &Bs[(w * 2 + 1) * 512];

  f32x4 acc[4][4] = {};

  for (int k0 = 0; k0 < K; k0 += 32) {
    __syncthreads();
    gl_lds16(gA0 + k0, lA0);
    gl_lds16(gA1 + k0, lA1);
    gl_lds16(gB0 + k0, lB0);
    gl_lds16(gB1 + k0, lB1);
    __syncthreads();
    bf16x8 af[4], bfr[4];
#pragma unroll
    for (int mt = 0; mt < 4; ++mt)
      af[mt] = *(const bf16x8*)&As[(wm * 4 + mt) * 512 + lane * 8];
#pragma unroll
    for (int nt = 0; nt < 4; ++nt)
      bfr[nt] = *(const bf16x8*)&Bs[(wn * 4 + nt) * 512 + lane * 8];
#pragma unroll
    for (int mt = 0; mt < 4; ++mt)
#pragma unroll
      for (int nt = 0; nt < 4; ++nt)
        acc[mt][nt] = __builtin_amdgcn_mfma_f32_16x16x32_bf16(
            af[mt], bfr[nt], acc[mt][nt], 0, 0, 0);
  }

  const int crow = (lane >> 4) * 4;
  const int ccol = lane & 15;
  const float* brow = bias + (size_t)e * strideBias + (size_t)bn * 128;
#pragma unroll
  for (int nt = 0; nt < 4; ++nt) {
    int col = wn * 64 + nt * 16 + ccol;
    float bv = brow[col];
#pragma unroll
    for (int mt = 0; mt < 4; ++mt) {
      f32x4 v = acc[mt][nt];
#pragma unroll
      for (int r = 0; r < 4; ++r) {
        float val = fmaxf(v[r] + bv, 0.f);   // FC1 always relu
        size_t row = (size_t)bm * 128 + wm * 64 + mt * 16 + crow + r;
        C[(size_t)e * strideC + row * ldc + (size_t)bn * 128 + col] = f2bf(val);
      }
    }
  }
}

// ---------- gate combine (sparse): go[t][b][:] = sum_{e: g>0} g * eo[e][pos[e][b]][:] ----------
__global__ __launch_bounds__(128) void combine_kernel(
    const unsigned short* __restrict__ eo, const float* __restrict__ g,
    unsigned short* __restrict__ go, const int* __restrict__ pos,
    int b0, int Bc) {
  const int bl = blockIdx.x, t = blockIdx.y;
  const int b = b0 + bl;
  const int o = threadIdx.x;
  const float* grow = g + ((size_t)t * 8192 + b) * 16;
  float a0 = 0, a1 = 0, a2 = 0, a3 = 0;
  for (int e = 0; e < 16; ++e) {
    float ge = grow[e];
    if (ge > 0.f) {
      int i = pos[e * Bc + bl];
      const unsigned short* row = eo + ((size_t)e * Bc + i) * 512;
      a0 = fmaf(ge, bf2f(row[o]), a0);
      a1 = fmaf(ge, bf2f(row[o + 128]), a1);
      a2 = fmaf(ge, bf2f(row[o + 256]), a2);
      a3 = fmaf(ge, bf2f(row[o + 384]), a3);
    }
  }
  unsigned short* orow = go + ((size_t)t * 8192 + b) * 512;
  orow[o] = f2bf(a0); orow[o + 128] = f2bf(a1);
  orow[o + 256] = f2bf(a2); orow[o + 384] = f2bf(a3);
}

// ---------- final: out[t*8192+b] = dot(t2[t][b][:256], Wh3[t]) + bh3[t] ----------
__global__ __launch_bounds__(256) void final_dot(const float* __restrict__ t2,
                                                 const float* __restrict__ Wh3,
                                                 const float* __restrict__ bh3,
                                                 float* __restrict__ out) {
  const int row = blockIdx.x * 4 + (threadIdx.x >> 6);  // one wave per row
  const int lane = threadIdx.x & 63;
  const int t = row >> 13;
  const float* trow = t2 + (size_t)row * 256;
  const float* w = Wh3 + t * 256;
  float s = 0.f;
#pragma unroll
  for (int j = 0; j < 4; ++j) s = fmaf(trow[lane + j * 64], w[lane + j * 64], s);
#pragma unroll
  for (int off = 32; off > 0; off >>= 1) s += __shfl_down(s, off, 64);
  if (lane == 0) out[row] = s + bh3[t];
}

// ---------- orchestration ----------
extern "C" void kernel_launch(void* const* d_in, const int* in_sizes, int n_in,
                              void* d_out, int out_size, void* d_ws, size_t ws_size,
                              hipStream_t stream) {
  (void)in_sizes; (void)n_in; (void)out_size;
  const float* x   = (const float*)d_in[0];
  const float* We1 = (const float*)d_in[1];
  const float* be1 = (const float*)d_in[2];
  const float* We2 = (const float*)d_in[3];
  const float* be2 = (const float*)d_in[4];
  const float* Wg  = (const float*)d_in[5];
  const float* Wn  = (const float*)d_in[6];
  const float* Wh1 = (const float*)d_in[7];
  const float* bh1 = (const float*)d_in[8];
  const float* Wh2 = (const float*)d_in[9];
  const float* bh2 = (const float*)d_in[10];
  const float* Wh3 = (const float*)d_in[11];
  const float* bh3 = (const float*)d_in[12];

  auto al = [](size_t v) { return (v + 255) & ~(size_t)255; };
  const size_t sz_xb   = al((size_t)8192 * 1024 * 2);
  const size_t sz_We1t = al((size_t)16 * 1024 * 1024 * 2);
  const size_t sz_We2t = al((size_t)16 * 512 * 1024 * 2);
  const size_t sz_Wh1t = al((size_t)2 * 512 * 512 * 2);
  const size_t sz_Wh2t = al((size_t)2 * 256 * 512 * 2);
  const size_t sz_g    = al((size_t)2 * 8192 * 16 * 4);
  const size_t sz_go   = al((size_t)2 * 8192 * 512 * 2);
  const size_t fixed = sz_xb + sz_We1t + sz_We2t + sz_Wh1t + sz_Wh2t + sz_g + sz_go;
  const size_t sz_t1 = al((size_t)2 * 8192 * 512 * 2);   // bf16
  const size_t sz_t2 = al((size_t)2 * 8192 * 256 * 4);   // f32
  const size_t sz_t12 = sz_t1 + sz_t2;
  const size_t sz_cnt = al((size_t)16 * 4);

  // pick largest batch chunk that fits (region hosts h+eo, later t1/t2)
  int Bc = 1024;
  {
    const int cands[4] = {8192, 4096, 2048, 1024};
    for (int ci = 0; ci < 4; ++ci) {
      int c = cands[ci];
      size_t region = al((size_t)16 * c * 1024 * 2) + al((size_t)16 * c * 512 * 2);
      if (region < sz_t12) region = sz_t12;
      size_t lists = sz_cnt + 2 * al((size_t)16 * c * 4);
      if (fixed + lists + region <= ws_size) { Bc = c; break; }
    }
  }
  const size_t sz_h = al((size_t)16 * Bc * 1024 * 2);

  char* ws = (char*)d_ws;
  size_t off = 0;
  auto carve = [&](size_t bytes) -> char* { char* p = ws + off; off += bytes; return p; };
  unsigned short* xb   = (unsigned short*)carve(sz_xb);
  unsigned short* We1t = (unsigned short*)carve(sz_We1t);
  unsigned short* We2t = (unsigned short*)carve(sz_We2t);
  unsigned short* Wh1t = (unsigned short*)carve(sz_Wh1t);
  unsigned short* Wh2t = (unsigned short*)carve(sz_Wh2t);
  float* g             = (float*)carve(sz_g);
  unsigned short* go   = (unsigned short*)carve(sz_go);
  int* count           = (int*)carve(sz_cnt);
  int* rowlist         = (int*)carve(al((size_t)16 * Bc * 4));
  int* pos             = (int*)carve(al((size_t)16 * Bc * 4));
  char* region         = ws + off;
  unsigned short* h    = (unsigned short*)region;            // [16][Bc][1024] bf16
  unsigned short* eo   = (unsigned short*)(region + sz_h);   // [16][Bc][512]  bf16
  unsigned short* t1   = (unsigned short*)region;            // aliases h (dead)
  float* t2            = (float*)(region + sz_t1);           // aliases region tail

  // prep: casts + weight transposes (B operands need N x K)
  cvt_x<<<8192, 256, 0, stream>>>(x, xb);
  transpose_bf16<<<dim3(32, 32, 16), 256, 0, stream>>>(We1, We1t, 1024, 1024);
  transpose_bf16<<<dim3(16, 32, 16), 256, 0, stream>>>(We2, We2t, 1024, 512);
  transpose_bf16<<<dim3(16, 16, 2), 256, 0, stream>>>(Wh1, Wh1t, 512, 512);
  transpose_bf16<<<dim3(8, 16, 2), 256, 0, stream>>>(Wh2, Wh2t, 512, 256);

  // gating (fp32, threefry noise, top-4 softmax)
  gating_kernel<<<1024, 256, 0, stream>>>(x, Wg, Wn, g);

  // sparse expert pipeline, chunked over batch
  for (int b0 = 0; b0 < 8192; b0 += Bc) {
    hipMemsetAsync(count, 0, 16 * sizeof(int), stream);
    build_routing<<<(Bc + 255) / 256, 256, 0, stream>>>(g, count, rowlist, pos, b0, Bc);
    // FC1 (gathered rows): h[e][i][1024]
    gemm_gather<<<dim3(Bc / 128, 8, 16), 256, 0, stream>>>(
        xb, 1024, We1t, 1024, (long long)1024 * 1024,
        h, 1024, (long long)Bc * 1024, be1, 1024, 1024,
        rowlist, count, b0, Bc);
    // FC2 (compact rows): eo[e][i][512]
    gemm_bt<false, true><<<dim3(Bc / 128, 4, 16), 256, 0, stream>>>(
        h, 1024, (long long)Bc * 1024,
        We2t, 1024, (long long)512 * 1024,
        eo, 512, (long long)Bc * 512, be2, 512, 1024, count);
    // weighted combine via pos lookup
    combine_kernel<<<dim3(Bc, 2), 128, 0, stream>>>(eo, g, go, pos, b0, Bc);
  }

  // towers (dense, full batch)
  gemm_bt<true, true><<<dim3(64, 4, 2), 256, 0, stream>>>(
      go, 512, (long long)8192 * 512, Wh1t, 512, (long long)512 * 512,
      t1, 512, (long long)8192 * 512, bh1, 512, 512, nullptr);
  gemm_bt<true, false><<<dim3(64, 2, 2), 256, 0, stream>>>(
      t1, 512, (long long)8192 * 512, Wh2t, 512, (long long)256 * 512,
      t2, 256, (long long)8192 * 256, bh2, 256, 512, nullptr);

  final_dot<<<4096, 256, 0, stream>>>(t2, Wh3, bh3, (float*)d_out);
}

// Round 4
// 938.357 us; speedup vs baseline: 1.3065x; 1.3065x over previous
//
#include <hip/hip_runtime.h>

#define AS1 __attribute__((address_space(1)))
#define AS3 __attribute__((address_space(3)))

typedef __bf16 bf16x8 __attribute__((ext_vector_type(8)));
typedef float f32x4 __attribute__((ext_vector_type(4)));

// ---------- small helpers ----------
__device__ __forceinline__ unsigned short f2bf(float f) {
  unsigned u = __float_as_uint(f);
  u += 0x7FFFu + ((u >> 16) & 1u);   // RNE
  return (unsigned short)(u >> 16);
}
__device__ __forceinline__ float bf2f(unsigned short u) {
  return __uint_as_float(((unsigned)u) << 16);
}

__device__ __forceinline__ void gl_lds16(const void* g, void* l) {
  // async global->LDS, 16B per lane; LDS dest = wave-uniform base + lane*16
  __builtin_amdgcn_global_load_lds((const AS1 unsigned int*)g,
                                   (AS3 unsigned int*)l, 16, 0, 0);
}

// Staging swizzle: lane slot s stages row (s>>2), source k-chunk ((s&3)-(row>>1))&3.
// Lanes 0-3 read one contiguous 64B row segment (coalesced, round-2 pattern);
// fragment read lane L uses chunk ((L>>4)+(frow>>1))&3 -> 2-way banks (free, m136).

// ---------- Threefry-2x32 (20 rounds), JAX-compatible ----------
__device__ __forceinline__ unsigned rotl32(unsigned v, int s) {
  return (v << s) | (v >> (32 - s));
}
__device__ __forceinline__ void threefry2x32(unsigned k0, unsigned k1,
                                             unsigned x0, unsigned x1,
                                             unsigned& o0, unsigned& o1) {
  const unsigned ks2 = k0 ^ k1 ^ 0x1BD11BDAu;
  x0 += k0; x1 += k1;
  x0 += x1; x1 = rotl32(x1, 13); x1 ^= x0;
  x0 += x1; x1 = rotl32(x1, 15); x1 ^= x0;
  x0 += x1; x1 = rotl32(x1, 26); x1 ^= x0;
  x0 += x1; x1 = rotl32(x1, 6);  x1 ^= x0;
  x0 += k1; x1 += ks2 + 1u;
  x0 += x1; x1 = rotl32(x1, 17); x1 ^= x0;
  x0 += x1; x1 = rotl32(x1, 29); x1 ^= x0;
  x0 += x1; x1 = rotl32(x1, 16); x1 ^= x0;
  x0 += x1; x1 = rotl32(x1, 24); x1 ^= x0;
  x0 += ks2; x1 += k0 + 2u;
  x0 += x1; x1 = rotl32(x1, 13); x1 ^= x0;
  x0 += x1; x1 = rotl32(x1, 15); x1 ^= x0;
  x0 += x1; x1 = rotl32(x1, 26); x1 ^= x0;
  x0 += x1; x1 = rotl32(x1, 6);  x1 ^= x0;
  x0 += k0; x1 += k1 + 3u;
  x0 += x1; x1 = rotl32(x1, 17); x1 ^= x0;
  x0 += x1; x1 = rotl32(x1, 29); x1 ^= x0;
  x0 += x1; x1 = rotl32(x1, 16); x1 ^= x0;
  x0 += x1; x1 = rotl32(x1, 24); x1 ^= x0;
  x0 += k1; x1 += ks2 + 4u;
  x0 += x1; x1 = rotl32(x1, 13); x1 ^= x0;
  x0 += x1; x1 = rotl32(x1, 15); x1 ^= x0;
  x0 += x1; x1 = rotl32(x1, 26); x1 ^= x0;
  x0 += x1; x1 = rotl32(x1, 6);  x1 ^= x0;
  o0 = x0 + ks2; o1 = x1 + k0 + 5u;
}

// XLA f32 erf_inv (Giles polynomial)
__device__ __forceinline__ float erfinv32(float x) {
  float w = -log1pf(-x * x);
  float p;
  if (w < 5.f) {
    w = w - 2.5f;
    p = 2.81022636e-08f;
    p = fmaf(p, w, 3.43273939e-07f);
    p = fmaf(p, w, -3.5233877e-06f);
    p = fmaf(p, w, -4.39150654e-06f);
    p = fmaf(p, w, 0.00021858087f);
    p = fmaf(p, w, -0.00125372503f);
    p = fmaf(p, w, -0.00417768164f);
    p = fmaf(p, w, 0.246640727f);
    p = fmaf(p, w, 1.50140941f);
  } else {
    w = sqrtf(w) - 3.f;
    p = -0.000200214257f;
    p = fmaf(p, w, 0.000100950558f);
    p = fmaf(p, w, 0.00134934322f);
    p = fmaf(p, w, -0.00367342844f);
    p = fmaf(p, w, 0.00573950773f);
    p = fmaf(p, w, -0.0076224613f);
    p = fmaf(p, w, 0.00943887047f);
    p = fmaf(p, w, 1.00167406f);
    p = fmaf(p, w, 2.83297682f);
  }
  return p * x;
}

// bits -> N(0,1) exactly as jax.random.normal (f32)
__device__ __forceinline__ float bits_to_normal(unsigned bits) {
  float f = __uint_as_float((bits >> 9) | 0x3f800000u) - 1.0f;  // [0,1)
  const float lo = -0.99999994f;
  float u = fmaf(f, 2.0f, lo);
  u = fmaxf(u, lo);
  return 1.41421356f * erfinv32(u);
}

// ---------- conversion / transpose kernels ----------
__global__ __launch_bounds__(256) void cvt_x(const float* __restrict__ in,
                                             unsigned short* __restrict__ out) {
  const int i = blockIdx.x * 256 + threadIdx.x;
  const float4 v = ((const float4*)in)[i];
  ushort4 o;
  o.x = f2bf(v.x); o.y = f2bf(v.y); o.z = f2bf(v.z); o.w = f2bf(v.w);
  ((ushort4*)out)[i] = o;
}

// in: [batch][R][C] f32  ->  out: [batch][C][R] bf16
__global__ __launch_bounds__(256) void transpose_bf16(
    const float* __restrict__ in, unsigned short* __restrict__ out, int R, int C) {
  __shared__ float tile[32][33];
  const int bz = blockIdx.z;
  in  += (size_t)bz * R * C;
  out += (size_t)bz * R * C;
  const int c0 = blockIdx.x * 32, r0 = blockIdx.y * 32;
  const int tx = threadIdx.x & 31, ty = threadIdx.x >> 5;  // 32x8
#pragma unroll
  for (int i = 0; i < 32; i += 8)
    tile[ty + i][tx] = in[(size_t)(r0 + ty + i) * C + c0 + tx];
  __syncthreads();
#pragma unroll
  for (int i = 0; i < 32; i += 8)
    out[(size_t)(c0 + ty + i) * R + r0 + tx] = f2bf(tile[tx][ty + i]);
}

// ---------- gating: mean/std/noise/top-k/softmax, all fp32 ----------
__global__ __launch_bounds__(256) void gating_kernel(
    const float* __restrict__ x, const float* __restrict__ Wg,
    const float* __restrict__ Wn, float* __restrict__ g) {
  __shared__ float xs[8][1024];
  __shared__ float partial[64][4][8];
  __shared__ float meanS[2][8][16];
  __shared__ float stdS[2][8][16];
  __shared__ float noisyS[2][8][16];
  const int tid = threadIdx.x;
  const int b0 = blockIdx.x * 8;
  for (int idx = tid; idx < 8 * 1024; idx += 256) {
    int r = idx >> 10, c = idx & 1023;
    xs[r][c] = x[(size_t)(b0 + r) * 1024 + c];
  }
  __syncthreads();
  {
    const int c = tid & 63;          // column id: t*32 + which*16 + e
    const int q = tid >> 6;          // K-partition 0..3
    const int t = c >> 5, which = (c >> 4) & 1, e = c & 15;
    const float* Wcol = (which ? Wn : Wg) + (size_t)t * 1024 * 16 + e;
    float acc[8] = {0, 0, 0, 0, 0, 0, 0, 0};
    const int i0 = q * 256;
    for (int i = i0; i < i0 + 256; ++i) {
      float w = Wcol[(size_t)i * 16];
#pragma unroll
      for (int r = 0; r < 8; ++r) acc[r] = fmaf(w, xs[r][i], acc[r]);
    }
#pragma unroll
    for (int r = 0; r < 8; ++r) partial[c][q][r] = acc[r];
  }
  __syncthreads();
  for (int idx = tid; idx < 512; idx += 256) {
    int c = idx >> 3, r = idx & 7;
    float s = partial[c][0][r] + partial[c][1][r] + partial[c][2][r] + partial[c][3][r];
    int t = c >> 5, which = (c >> 4) & 1, e = c & 15;
    if (which)  // softplus
      stdS[t][r][e] = fmaxf(s, 0.f) + log1pf(expf(-fabsf(s)));
    else
      meanS[t][r][e] = s;
  }
  __syncthreads();
  if (tid < 128) {
    int r = tid >> 4, e = tid & 15;
    unsigned p = (unsigned)((b0 + r) * 16 + e);
#pragma unroll
    for (int t = 0; t < 2; ++t) {
      unsigned n = (unsigned)t * 131072u + p;  // flat index into (T,B,E)
      unsigned y0, y1;
      threefry2x32(0u, 42u, 0u, n, y0, y1);    // partitionable: counter=(0, n)
      float nrm = bits_to_normal(y0 ^ y1);
      noisyS[t][r][e] = meanS[t][r][e] + nrm * stdS[t][r][e];
    }
  }
  __syncthreads();
  if (tid < 16) {
    int r = tid >> 1, t = tid & 1;
    float v[16];
#pragma unroll
    for (int e = 0; e < 16; ++e) v[e] = noisyS[t][r][e];
    float m0 = -1e30f, m1 = -1e30f, m2 = -1e30f, m3 = -1e30f;
#pragma unroll
    for (int e = 0; e < 16; ++e) {
      float val = v[e];
      if (val > m0) { m3 = m2; m2 = m1; m1 = m0; m0 = val; }
      else if (val > m1) { m3 = m2; m2 = m1; m1 = val; }
      else if (val > m2) { m3 = m2; m2 = val; }
      else if (val > m3) { m3 = val; }
    }
    float sum = 0.f, ge[16];
#pragma unroll
    for (int e = 0; e < 16; ++e) {
      if (v[e] >= m3) { ge[e] = expf(v[e] - m0); sum += ge[e]; }
      else ge[e] = 0.f;
    }
    float inv = 1.f / sum;
    float* grow = g + ((size_t)t * 8192 + (b0 + r)) * 16;
#pragma unroll
    for (int e = 0; e < 16; ++e) grow[e] = ge[e] * inv;
  }
}

// ---------- routing lists: per expert, rows used by either task ----------
__global__ __launch_bounds__(256) void build_routing(
    const float* __restrict__ g, int* __restrict__ count,
    int* __restrict__ rowlist, int* __restrict__ pos, int b0, int Bc) {
  const int bl = blockIdx.x * 256 + threadIdx.x;
  if (bl >= Bc) return;
  const int b = b0 + bl;
  const float* g0 = g + (size_t)b * 16;
  const float* g1 = g + (size_t)(8192 + b) * 16;
#pragma unroll
  for (int e = 0; e < 16; ++e) {
    if (g0[e] > 0.f || g1[e] > 0.f) {
      int i = atomicAdd(&count[e], 1);
      rowlist[e * Bc + i] = bl;
      pos[e * Bc + bl] = i;
    }
  }
}

// ---------- bf16 MFMA GEMM: C[M,N] = A[M,K] @ Bt[N,K]^T (+bias, opt relu) ----------
// Coalesced global staging (round-2 order) + XOR-swizzled LDS (conflict-free reads)
template <bool RELU, bool OUT_BF16>
__global__ __launch_bounds__(256) void gemm_bt(
    const unsigned short* __restrict__ A, int lda, long long strideA,
    const unsigned short* __restrict__ Bt, int ldb, long long strideB,
    void* __restrict__ Cv, int ldc, long long strideC,
    const float* __restrict__ bias, int strideBias, int K,
    const int* __restrict__ count) {
  __shared__ __align__(16) unsigned short As[8 * 512];
  __shared__ __align__(16) unsigned short Bs[8 * 512];
  const int tid = threadIdx.x;
  const int w = tid >> 6, lane = tid & 63;
  const int wm = w >> 1, wn = w & 1;
  const int bm = blockIdx.x, bn = blockIdx.y, bz = blockIdx.z;
  if (count && bm * 128 >= count[bz]) return;   // sparse early-exit

  const unsigned short* Ab = A + (size_t)bz * strideA + (size_t)bm * 128 * lda;
  const unsigned short* Bb = Bt + (size_t)bz * strideB + (size_t)bn * 128 * ldb;

  const int sr = lane >> 2;                          // row within 16-row subtile
  const int sc = (((lane & 3) - (sr >> 1)) & 3) * 8; // swizzled source k-chunk
  const unsigned short* gA0 = Ab + (size_t)(w * 32 + sr) * lda + sc;
  const unsigned short* gA1 = gA0 + (size_t)16 * lda;
  const unsigned short* gB0 = Bb + (size_t)(w * 32 + sr) * ldb + sc;
  const unsigned short* gB1 = gB0 + (size_t)16 * ldb;
  unsigned short* lA0 = &As[(w * 2) * 512];
  unsigned short* lA1 = &As[(w * 2 + 1) * 512];
  unsigned short* lB0 = &Bs[(w * 2) * 512];
  unsigned short* lB1 = &Bs[(w * 2 + 1) * 512];

  f32x4 acc[4][4] = {};
  const int frow = lane & 15;
  const int rcA = (((lane >> 4) + (frow >> 1)) & 3) * 8;  // swizzled read chunk

  for (int k0 = 0; k0 < K; k0 += 32) {
    __syncthreads();
    gl_lds16(gA0 + k0, lA0);
    gl_lds16(gA1 + k0, lA1);
    gl_lds16(gB0 + k0, lB0);
    gl_lds16(gB1 + k0, lB1);
    __syncthreads();
    bf16x8 af[4], bfr[4];
#pragma unroll
    for (int mt = 0; mt < 4; ++mt)
      af[mt] = *(const bf16x8*)&As[(wm * 4 + mt) * 512 + frow * 32 + rcA];
#pragma unroll
    for (int nt = 0; nt < 4; ++nt)
      bfr[nt] = *(const bf16x8*)&Bs[(wn * 4 + nt) * 512 + frow * 32 + rcA];
#pragma unroll
    for (int mt = 0; mt < 4; ++mt)
#pragma unroll
      for (int nt = 0; nt < 4; ++nt)
        acc[mt][nt] = __builtin_amdgcn_mfma_f32_16x16x32_bf16(
            af[mt], bfr[nt], acc[mt][nt], 0, 0, 0);
  }

  // epilogue: C/D layout col=lane&15, row=(lane>>4)*4+r (m89-verified)
  const int crow = (lane >> 4) * 4;
  const int ccol = lane & 15;
  const float* brow = bias + (size_t)bz * strideBias + (size_t)bn * 128;
#pragma unroll
  for (int nt = 0; nt < 4; ++nt) {
    int col = wn * 64 + nt * 16 + ccol;
    float bv = brow[col];
#pragma unroll
    for (int mt = 0; mt < 4; ++mt) {
      f32x4 v = acc[mt][nt];
#pragma unroll
      for (int r = 0; r < 4; ++r) {
        float val = v[r] + bv;
        if (RELU) val = fmaxf(val, 0.f);
        size_t row = (size_t)bm * 128 + wm * 64 + mt * 16 + crow + r;
        size_t off = (size_t)bz * strideC + row * ldc + (size_t)bn * 128 + col;
        if (OUT_BF16) ((unsigned short*)Cv)[off] = f2bf(val);
        else          ((float*)Cv)[off] = val;
      }
    }
  }
}

// ---------- FC1 with row gather: h[e][i][:] = relu(x[rowlist[e][i]] @ We1[e]) ----------
__global__ __launch_bounds__(256) void gemm_gather(
    const unsigned short* __restrict__ A, int lda,          // xb dense [8192][K]
    const unsigned short* __restrict__ Bt, int ldb, long long strideB,
    unsigned short* __restrict__ C, int ldc, long long strideC,
    const float* __restrict__ bias, int strideBias, int K,
    const int* __restrict__ rowlist, const int* __restrict__ count,
    int b0, int Bc) {
  __shared__ __align__(16) unsigned short As[8 * 512];
  __shared__ __align__(16) unsigned short Bs[8 * 512];
  const int tid = threadIdx.x;
  const int w = tid >> 6, lane = tid & 63;
  const int wm = w >> 1, wn = w & 1;
  const int bm = blockIdx.x, bn = blockIdx.y, e = blockIdx.z;
  const int cnt = count[e];
  if (bm * 128 >= cnt) return;

  const int sr = lane >> 2;                          // row within subtile
  const int sc = (((lane & 3) - (sr >> 1)) & 3) * 8; // swizzled source k-chunk
  // gather A rows via rowlist (per-lane global source is legal; 4 lanes/row stay
  // within one 64B segment -> coalesced)
  const int i0 = bm * 128 + w * 32 + sr;
  const int i1 = i0 + 16;
  const int* rl = rowlist + (size_t)e * Bc;
  const int r0 = (i0 < cnt) ? rl[i0] : rl[0];
  const int r1 = (i1 < cnt) ? rl[i1] : rl[0];
  const unsigned short* gA0 = A + (size_t)(b0 + r0) * lda + sc;
  const unsigned short* gA1 = A + (size_t)(b0 + r1) * lda + sc;
  const unsigned short* Bb = Bt + (size_t)e * strideB + (size_t)bn * 128 * ldb;
  const unsigned short* gB0 = Bb + (size_t)(w * 32 + sr) * ldb + sc;
  const unsigned short* gB1 = gB0 + (size_t)16 * ldb;
  unsigned short* lA0 = &As[(w * 2) * 512];
  unsigned short* lA1 = &As[(w * 2 + 1) * 512];
  unsigned short* lB0 = &Bs[(w * 2) * 512];
  unsigned short* lB1 = &Bs[(w * 2 + 1) * 512];

  f32x4 acc[4][4] = {};
  const int frow = lane & 15;
  const int rcA = (((lane >> 4) + (frow >> 1)) & 3) * 8;

  for (int k0 = 0; k0 < K; k0 += 32) {
    __syncthreads();
    gl_lds16(gA0 + k0, lA0);
    gl_lds16(gA1 + k0, lA1);
    gl_lds16(gB0 + k0, lB0);
    gl_lds16(gB1 + k0, lB1);
    __syncthreads();
    bf16x8 af[4], bfr[4];
#pragma unroll
    for (int mt = 0; mt < 4; ++mt)
      af[mt] = *(const bf16x8*)&As[(wm * 4 + mt) * 512 + frow * 32 + rcA];
#pragma unroll
    for (int nt = 0; nt < 4; ++nt)
      bfr[nt] = *(const bf16x8*)&Bs[(wn * 4 + nt) * 512 + frow * 32 + rcA];
#pragma unroll
    for (int mt = 0; mt < 4; ++mt)
#pragma unroll
      for (int nt = 0; nt < 4; ++nt)
        acc[mt][nt] = __builtin_amdgcn_mfma_f32_16x16x32_bf16(
            af[mt], bfr[nt], acc[mt][nt], 0, 0, 0);
  }

  const int crow = (lane >> 4) * 4;
  const int ccol = lane & 15;
  const float* brow = bias + (size_t)e * strideBias + (size_t)bn * 128;
#pragma unroll
  for (int nt = 0; nt < 4; ++nt) {
    int col = wn * 64 + nt * 16 + ccol;
    float bv = brow[col];
#pragma unroll
    for (int mt = 0; mt < 4; ++mt) {
      f32x4 v = acc[mt][nt];
#pragma unroll
      for (int r = 0; r < 4; ++r) {
        float val = fmaxf(v[r] + bv, 0.f);   // FC1 always relu
        size_t row = (size_t)bm * 128 + wm * 64 + mt * 16 + crow + r;
        C[(size_t)e * strideC + row * ldc + (size_t)bn * 128 + col] = f2bf(val);
      }
    }
  }
}

// ---------- gate combine (sparse): go[t][b][:] = sum_{e: g>0} g * eo[e][pos[e][b]][:] ----------
__global__ __launch_bounds__(128) void combine_kernel(
    const unsigned short* __restrict__ eo, const float* __restrict__ g,
    unsigned short* __restrict__ go, const int* __restrict__ pos,
    int b0, int Bc) {
  const int bl = blockIdx.x, t = blockIdx.y;
  const int b = b0 + bl;
  const int o = threadIdx.x;
  const float* grow = g + ((size_t)t * 8192 + b) * 16;
  float a0 = 0, a1 = 0, a2 = 0, a3 = 0;
  for (int e = 0; e < 16; ++e) {
    float ge = grow[e];
    if (ge > 0.f) {
      int i = pos[e * Bc + bl];
      const unsigned short* row = eo + ((size_t)e * Bc + i) * 512;
      a0 = fmaf(ge, bf2f(row[o]), a0);
      a1 = fmaf(ge, bf2f(row[o + 128]), a1);
      a2 = fmaf(ge, bf2f(row[o + 256]), a2);
      a3 = fmaf(ge, bf2f(row[o + 384]), a3);
    }
  }
  unsigned short* orow = go + ((size_t)t * 8192 + b) * 512;
  orow[o] = f2bf(a0); orow[o + 128] = f2bf(a1);
  orow[o + 256] = f2bf(a2); orow[o + 384] = f2bf(a3);
}

// ---------- final: out[t*8192+b] = dot(t2[t][b][:256], Wh3[t]) + bh3[t] ----------
__global__ __launch_bounds__(256) void final_dot(const float* __restrict__ t2,
                                                 const float* __restrict__ Wh3,
                                                 const float* __restrict__ bh3,
                                                 float* __restrict__ out) {
  const int row = blockIdx.x * 4 + (threadIdx.x >> 6);  // one wave per row
  const int lane = threadIdx.x & 63;
  const int t = row >> 13;
  const float* trow = t2 + (size_t)row * 256;
  const float* w = Wh3 + t * 256;
  float s = 0.f;
#pragma unroll
  for (int j = 0; j < 4; ++j) s = fmaf(trow[lane + j * 64], w[lane + j * 64], s);
#pragma unroll
  for (int off = 32; off > 0; off >>= 1) s += __shfl_down(s, off, 64);
  if (lane == 0) out[row] = s + bh3[t];
}

// ---------- orchestration ----------
extern "C" void kernel_launch(void* const* d_in, const int* in_sizes, int n_in,
                              void* d_out, int out_size, void* d_ws, size_t ws_size,
                              hipStream_t stream) {
  (void)in_sizes; (void)n_in; (void)out_size;
  const float* x   = (const float*)d_in[0];
  const float* We1 = (const float*)d_in[1];
  const float* be1 = (const float*)d_in[2];
  const float* We2 = (const float*)d_in[3];
  const float* be2 = (const float*)d_in[4];
  const float* Wg  = (const float*)d_in[5];
  const float* Wn  = (const float*)d_in[6];
  const float* Wh1 = (const float*)d_in[7];
  const float* bh1 = (const float*)d_in[8];
  const float* Wh2 = (const float*)d_in[9];
  const float* bh2 = (const float*)d_in[10];
  const float* Wh3 = (const float*)d_in[11];
  const float* bh3 = (const float*)d_in[12];

  auto al = [](size_t v) { return (v + 255) & ~(size_t)255; };
  const size_t sz_xb   = al((size_t)8192 * 1024 * 2);
  const size_t sz_We1t = al((size_t)16 * 1024 * 1024 * 2);
  const size_t sz_We2t = al((size_t)16 * 512 * 1024 * 2);
  const size_t sz_Wh1t = al((size_t)2 * 512 * 512 * 2);
  const size_t sz_Wh2t = al((size_t)2 * 256 * 512 * 2);
  const size_t sz_g    = al((size_t)2 * 8192 * 16 * 4);
  const size_t sz_go   = al((size_t)2 * 8192 * 512 * 2);
  const size_t fixed = sz_xb + sz_We1t + sz_We2t + sz_Wh1t + sz_Wh2t + sz_g + sz_go;
  const size_t sz_t1 = al((size_t)2 * 8192 * 512 * 2);   // bf16
  const size_t sz_t2 = al((size_t)2 * 8192 * 256 * 4);   // f32
  const size_t sz_t12 = sz_t1 + sz_t2;
  const size_t sz_cnt = al((size_t)16 * 4);

  // pick largest batch chunk that fits (region hosts h+eo, later t1/t2)
  int Bc = 1024;
  {
    const int cands[4] = {8192, 4096, 2048, 1024};
    for (int ci = 0; ci < 4; ++ci) {
      int c = cands[ci];
      size_t region = al((size_t)16 * c * 1024 * 2) + al((size_t)16 * c * 512 * 2);
      if (region < sz_t12) region = sz_t12;
      size_t lists = sz_cnt + 2 * al((size_t)16 * c * 4);
      if (fixed + lists + region <= ws_size) { Bc = c; break; }
    }
  }
  const size_t sz_h = al((size_t)16 * Bc * 1024 * 2);

  char* ws = (char*)d_ws;
  size_t off = 0;
  auto carve = [&](size_t bytes) -> char* { char* p = ws + off; off += bytes; return p; };
  unsigned short* xb   = (unsigned short*)carve(sz_xb);
  unsigned short* We1t = (unsigned short*)carve(sz_We1t);
  unsigned short* We2t = (unsigned short*)carve(sz_We2t);
  unsigned short* Wh1t = (unsigned short*)carve(sz_Wh1t);
  unsigned short* Wh2t = (unsigned short*)carve(sz_Wh2t);
  float* g             = (float*)carve(sz_g);
  unsigned short* go   = (unsigned short*)carve(sz_go);
  int* count           = (int*)carve(sz_cnt);
  int* rowlist         = (int*)carve(al((size_t)16 * Bc * 4));
  int* pos             = (int*)carve(al((size_t)16 * Bc * 4));
  char* region         = ws + off;
  unsigned short* h    = (unsigned short*)region;            // [16][Bc][1024] bf16
  unsigned short* eo   = (unsigned short*)(region + sz_h);   // [16][Bc][512]  bf16
  unsigned short* t1   = (unsigned short*)region;            // aliases h (dead)
  float* t2            = (float*)(region + sz_t1);           // aliases region tail

  // prep: casts + weight transposes (B operands need N x K)
  cvt_x<<<8192, 256, 0, stream>>>(x, xb);
  transpose_bf16<<<dim3(32, 32, 16), 256, 0, stream>>>(We1, We1t, 1024, 1024);
  transpose_bf16<<<dim3(16, 32, 16), 256, 0, stream>>>(We2, We2t, 1024, 512);
  transpose_bf16<<<dim3(16, 16, 2), 256, 0, stream>>>(Wh1, Wh1t, 512, 512);
  transpose_bf16<<<dim3(8, 16, 2), 256, 0, stream>>>(Wh2, Wh2t, 512, 256);

  // gating (fp32, threefry noise, top-4 softmax)
  gating_kernel<<<1024, 256, 0, stream>>>(x, Wg, Wn, g);

  // sparse expert pipeline, chunked over batch
  for (int b0 = 0; b0 < 8192; b0 += Bc) {
    hipMemsetAsync(count, 0, 16 * sizeof(int), stream);
    build_routing<<<(Bc + 255) / 256, 256, 0, stream>>>(g, count, rowlist, pos, b0, Bc);
    // FC1 (gathered rows): h[e][i][1024]
    gemm_gather<<<dim3(Bc / 128, 8, 16), 256, 0, stream>>>(
        xb, 1024, We1t, 1024, (long long)1024 * 1024,
        h, 1024, (long long)Bc * 1024, be1, 1024, 1024,
        rowlist, count, b0, Bc);
    // FC2 (compact rows): eo[e][i][512]
    gemm_bt<false, true><<<dim3(Bc / 128, 4, 16), 256, 0, stream>>>(
        h, 1024, (long long)Bc * 1024,
        We2t, 1024, (long long)512 * 1024,
        eo, 512, (long long)Bc * 512, be2, 512, 1024, count);
    // weighted combine via pos lookup
    combine_kernel<<<dim3(Bc, 2), 128, 0, stream>>>(eo, g, go, pos, b0, Bc);
  }

  // towers (dense, full batch)
  gemm_bt<true, true><<<dim3(64, 4, 2), 256, 0, stream>>>(
      go, 512, (long long)8192 * 512, Wh1t, 512, (long long)512 * 512,
      t1, 512, (long long)8192 * 512, bh1, 512, 512, nullptr);
  gemm_bt<true, false><<<dim3(64, 2, 2), 256, 0, stream>>>(
      t1, 512, (long long)8192 * 512, Wh2t, 512, (long long)256 * 512,
      t2, 256, (long long)8192 * 256, bh2, 256, 512, nullptr);

  final_dot<<<4096, 256, 0, stream>>>(t2, Wh3, bh3, (float*)d_out);
}

// Round 5
// 921.572 us; speedup vs baseline: 1.3303x; 1.0182x over previous
//
#include <hip/hip_runtime.h>

#define AS1 __attribute__((address_space(1)))
#define AS3 __attribute__((address_space(3)))

typedef __bf16 bf16x8 __attribute__((ext_vector_type(8)));
typedef float f32x4 __attribute__((ext_vector_type(4)));

// ---------- small helpers ----------
__device__ __forceinline__ unsigned short f2bf(float f) {
  unsigned u = __float_as_uint(f);
  u += 0x7FFFu + ((u >> 16) & 1u);   // RNE
  return (unsigned short)(u >> 16);
}
__device__ __forceinline__ float bf2f(unsigned short u) {
  return __uint_as_float(((unsigned)u) << 16);
}

__device__ __forceinline__ void gl_lds16(const void* g, void* l) {
  // async global->LDS, 16B per lane; LDS dest = wave-uniform base + lane*16
  __builtin_amdgcn_global_load_lds((const AS1 unsigned int*)g,
                                   (AS3 unsigned int*)l, 16, 0, 0);
}

// Staging swizzle (round-4, verified conflict-free + coalesced):
// lane slot s stages row (s>>2), source k-chunk ((s&3)-(row>>1))&3;
// fragment read lane L uses chunk ((L>>4)+(frow>>1))&3.

// ---------- Threefry-2x32 (20 rounds), JAX-compatible ----------
__device__ __forceinline__ unsigned rotl32(unsigned v, int s) {
  return (v << s) | (v >> (32 - s));
}
__device__ __forceinline__ void threefry2x32(unsigned k0, unsigned k1,
                                             unsigned x0, unsigned x1,
                                             unsigned& o0, unsigned& o1) {
  const unsigned ks2 = k0 ^ k1 ^ 0x1BD11BDAu;
  x0 += k0; x1 += k1;
  x0 += x1; x1 = rotl32(x1, 13); x1 ^= x0;
  x0 += x1; x1 = rotl32(x1, 15); x1 ^= x0;
  x0 += x1; x1 = rotl32(x1, 26); x1 ^= x0;
  x0 += x1; x1 = rotl32(x1, 6);  x1 ^= x0;
  x0 += k1; x1 += ks2 + 1u;
  x0 += x1; x1 = rotl32(x1, 17); x1 ^= x0;
  x0 += x1; x1 = rotl32(x1, 29); x1 ^= x0;
  x0 += x1; x1 = rotl32(x1, 16); x1 ^= x0;
  x0 += x1; x1 = rotl32(x1, 24); x1 ^= x0;
  x0 += ks2; x1 += k0 + 2u;
  x0 += x1; x1 = rotl32(x1, 13); x1 ^= x0;
  x0 += x1; x1 = rotl32(x1, 15); x1 ^= x0;
  x0 += x1; x1 = rotl32(x1, 26); x1 ^= x0;
  x0 += x1; x1 = rotl32(x1, 6);  x1 ^= x0;
  x0 += k0; x1 += k1 + 3u;
  x0 += x1; x1 = rotl32(x1, 17); x1 ^= x0;
  x0 += x1; x1 = rotl32(x1, 29); x1 ^= x0;
  x0 += x1; x1 = rotl32(x1, 16); x1 ^= x0;
  x0 += x1; x1 = rotl32(x1, 24); x1 ^= x0;
  x0 += k1; x1 += ks2 + 4u;
  x0 += x1; x1 = rotl32(x1, 13); x1 ^= x0;
  x0 += x1; x1 = rotl32(x1, 15); x1 ^= x0;
  x0 += x1; x1 = rotl32(x1, 26); x1 ^= x0;
  x0 += x1; x1 = rotl32(x1, 6);  x1 ^= x0;
  o0 = x0 + ks2; o1 = x1 + k0 + 5u;
}

// XLA f32 erf_inv (Giles polynomial)
__device__ __forceinline__ float erfinv32(float x) {
  float w = -log1pf(-x * x);
  float p;
  if (w < 5.f) {
    w = w - 2.5f;
    p = 2.81022636e-08f;
    p = fmaf(p, w, 3.43273939e-07f);
    p = fmaf(p, w, -3.5233877e-06f);
    p = fmaf(p, w, -4.39150654e-06f);
    p = fmaf(p, w, 0.00021858087f);
    p = fmaf(p, w, -0.00125372503f);
    p = fmaf(p, w, -0.00417768164f);
    p = fmaf(p, w, 0.246640727f);
    p = fmaf(p, w, 1.50140941f);
  } else {
    w = sqrtf(w) - 3.f;
    p = -0.000200214257f;
    p = fmaf(p, w, 0.000100950558f);
    p = fmaf(p, w, 0.00134934322f);
    p = fmaf(p, w, -0.00367342844f);
    p = fmaf(p, w, 0.00573950773f);
    p = fmaf(p, w, -0.0076224613f);
    p = fmaf(p, w, 0.00943887047f);
    p = fmaf(p, w, 1.00167406f);
    p = fmaf(p, w, 2.83297682f);
  }
  return p * x;
}

// bits -> N(0,1) exactly as jax.random.normal (f32)
__device__ __forceinline__ float bits_to_normal(unsigned bits) {
  float f = __uint_as_float((bits >> 9) | 0x3f800000u) - 1.0f;  // [0,1)
  const float lo = -0.99999994f;
  float u = fmaf(f, 2.0f, lo);
  u = fmaxf(u, lo);
  return 1.41421356f * erfinv32(u);
}

// ---------- conversion / transpose kernels ----------
__global__ __launch_bounds__(256) void cvt_x(const float* __restrict__ in,
                                             unsigned short* __restrict__ out) {
  const int i = blockIdx.x * 256 + threadIdx.x;
  const float4 v = ((const float4*)in)[i];
  ushort4 o;
  o.x = f2bf(v.x); o.y = f2bf(v.y); o.z = f2bf(v.z); o.w = f2bf(v.w);
  ((ushort4*)out)[i] = o;
}

// in: [batch][R][C] f32  ->  out: [batch][C][R] bf16
__global__ __launch_bounds__(256) void transpose_bf16(
    const float* __restrict__ in, unsigned short* __restrict__ out, int R, int C) {
  __shared__ float tile[32][33];
  const int bz = blockIdx.z;
  in  += (size_t)bz * R * C;
  out += (size_t)bz * R * C;
  const int c0 = blockIdx.x * 32, r0 = blockIdx.y * 32;
  const int tx = threadIdx.x & 31, ty = threadIdx.x >> 5;  // 32x8
#pragma unroll
  for (int i = 0; i < 32; i += 8)
    tile[ty + i][tx] = in[(size_t)(r0 + ty + i) * C + c0 + tx];
  __syncthreads();
#pragma unroll
  for (int i = 0; i < 32; i += 8)
    out[(size_t)(c0 + ty + i) * R + r0 + tx] = f2bf(tile[tx][ty + i]);
}

// ---------- gating: mean/std/noise/top-k/softmax, all fp32 ----------
__global__ __launch_bounds__(256) void gating_kernel(
    const float* __restrict__ x, const float* __restrict__ Wg,
    const float* __restrict__ Wn, float* __restrict__ g) {
  __shared__ float xs[8][1024];
  __shared__ float partial[64][4][8];
  __shared__ float meanS[2][8][16];
  __shared__ float stdS[2][8][16];
  __shared__ float noisyS[2][8][16];
  const int tid = threadIdx.x;
  const int b0 = blockIdx.x * 8;
  for (int idx = tid; idx < 8 * 1024; idx += 256) {
    int r = idx >> 10, c = idx & 1023;
    xs[r][c] = x[(size_t)(b0 + r) * 1024 + c];
  }
  __syncthreads();
  {
    const int c = tid & 63;          // column id: t*32 + which*16 + e
    const int q = tid >> 6;          // K-partition 0..3
    const int t = c >> 5, which = (c >> 4) & 1, e = c & 15;
    const float* Wcol = (which ? Wn : Wg) + (size_t)t * 1024 * 16 + e;
    float acc[8] = {0, 0, 0, 0, 0, 0, 0, 0};
    const int i0 = q * 256;
    for (int i = i0; i < i0 + 256; ++i) {
      float w = Wcol[(size_t)i * 16];
#pragma unroll
      for (int r = 0; r < 8; ++r) acc[r] = fmaf(w, xs[r][i], acc[r]);
    }
#pragma unroll
    for (int r = 0; r < 8; ++r) partial[c][q][r] = acc[r];
  }
  __syncthreads();
  for (int idx = tid; idx < 512; idx += 256) {
    int c = idx >> 3, r = idx & 7;
    float s = partial[c][0][r] + partial[c][1][r] + partial[c][2][r] + partial[c][3][r];
    int t = c >> 5, which = (c >> 4) & 1, e = c & 15;
    if (which)  // softplus
      stdS[t][r][e] = fmaxf(s, 0.f) + log1pf(expf(-fabsf(s)));
    else
      meanS[t][r][e] = s;
  }
  __syncthreads();
  if (tid < 128) {
    int r = tid >> 4, e = tid & 15;
    unsigned p = (unsigned)((b0 + r) * 16 + e);
#pragma unroll
    for (int t = 0; t < 2; ++t) {
      unsigned n = (unsigned)t * 131072u + p;  // flat index into (T,B,E)
      unsigned y0, y1;
      threefry2x32(0u, 42u, 0u, n, y0, y1);    // partitionable: counter=(0, n)
      float nrm = bits_to_normal(y0 ^ y1);
      noisyS[t][r][e] = meanS[t][r][e] + nrm * stdS[t][r][e];
    }
  }
  __syncthreads();
  if (tid < 16) {
    int r = tid >> 1, t = tid & 1;
    float v[16];
#pragma unroll
    for (int e = 0; e < 16; ++e) v[e] = noisyS[t][r][e];
    float m0 = -1e30f, m1 = -1e30f, m2 = -1e30f, m3 = -1e30f;
#pragma unroll
    for (int e = 0; e < 16; ++e) {
      float val = v[e];
      if (val > m0) { m3 = m2; m2 = m1; m1 = m0; m0 = val; }
      else if (val > m1) { m3 = m2; m2 = m1; m1 = val; }
      else if (val > m2) { m3 = m2; m2 = val; }
      else if (val > m3) { m3 = val; }
    }
    float sum = 0.f, ge[16];
#pragma unroll
    for (int e = 0; e < 16; ++e) {
      if (v[e] >= m3) { ge[e] = expf(v[e] - m0); sum += ge[e]; }
      else ge[e] = 0.f;
    }
    float inv = 1.f / sum;
    float* grow = g + ((size_t)t * 8192 + (b0 + r)) * 16;
#pragma unroll
    for (int e = 0; e < 16; ++e) grow[e] = ge[e] * inv;
  }
}

// ---------- global sorted routing: one block per expert, rank-scan ----------
// rowlist[e*8192 + r] = b (sorted by b), pos[e*8192 + b] = r,
// cnt[e*NC + ch] = rows of chunk ch routed to e. Deterministic.
__global__ __launch_bounds__(256) void routing_scan(
    const float* __restrict__ g, int* __restrict__ cnt,
    int* __restrict__ rowlist, int* __restrict__ pos, int NC) {
  const int e = blockIdx.x;
  const int t = threadIdx.x;
  __shared__ int sc_[256];
  // flags for rows [t*32, t*32+32)
  unsigned flags = 0;
  int c = 0;
#pragma unroll 4
  for (int j = 0; j < 32; ++j) {
    int b = t * 32 + j;
    bool r = (g[(size_t)b * 16 + e] > 0.f) || (g[(size_t)(8192 + b) * 16 + e] > 0.f);
    flags |= (r ? 1u : 0u) << j;
    c += r ? 1 : 0;
  }
  sc_[t] = c;
  __syncthreads();
  for (int ofs = 1; ofs < 256; ofs <<= 1) {   // Hillis-Steele inclusive scan
    int add = (t >= ofs) ? sc_[t - ofs] : 0;
    __syncthreads();
    sc_[t] += add;
    __syncthreads();
  }
  const int base = sc_[t] - c;  // exclusive prefix = my first rank
  int local = 0;
  for (int j = 0; j < 32; ++j) {
    if ((flags >> j) & 1u) {
      int b = t * 32 + j;
      int r = base + local++;
      rowlist[e * 8192 + r] = b;
      pos[e * 8192 + b] = r;
    }
  }
  const int tpc = 256 / NC;     // threads per chunk (chunk = 8192/NC rows)
  if (((t + 1) & (tpc - 1)) == 0) {
    int ch = t / tpc;
    int lo = (ch == 0) ? 0 : sc_[ch * tpc - 1];
    cnt[e * NC + ch] = sc_[t] - lo;
  }
}

// startT[e*NC+ch] = rank base of chunk ch in expert e's list;
// offT[ch*16+e] = compact h/eo slot base of expert e within chunk ch.
__global__ void make_tables(const int* __restrict__ cnt, int* __restrict__ startT,
                            int* __restrict__ offT, int NC) {
  if (threadIdx.x == 0 && blockIdx.x == 0) {
    for (int e = 0; e < 16; ++e) {
      int s = 0;
      for (int c = 0; c < NC; ++c) { startT[e * NC + c] = s; s += cnt[e * NC + c]; }
    }
    for (int c = 0; c < NC; ++c) {
      int s = 0;
      for (int ee = 0; ee < 16; ++ee) { offT[c * 16 + ee] = s; s += cnt[ee * NC + c]; }
    }
  }
}

// ---------- FC1: h[off+i][:] = relu(x[rowlist[i]] @ We1[e] + be1[e]), compact ----------
__global__ __launch_bounds__(256) void gemm_fc1(
    const unsigned short* __restrict__ xb,            // [8192][1024]
    const unsigned short* __restrict__ Bt,            // We1t [16][1024][1024]
    unsigned short* __restrict__ h,                   // compact [cap][1024]
    const float* __restrict__ bias,                   // be1 [16][1024]
    const int* __restrict__ rowlist, const int* __restrict__ cnt,
    const int* __restrict__ startT, const int* __restrict__ offT,
    int ch, int NC) {
  __shared__ __align__(16) unsigned short As[8 * 512];
  __shared__ __align__(16) unsigned short Bs[8 * 512];
  const int e = blockIdx.z;
  const int cnt_ec = cnt[e * NC + ch];
  const int bm = blockIdx.x, bn = blockIdx.y;
  if (bm * 128 >= cnt_ec) return;   // sparse early-exit
  const int tid = threadIdx.x;
  const int w = tid >> 6, lane = tid & 63;
  const int wm = w >> 1, wn = w & 1;

  const int* rl = rowlist + e * 8192 + startT[e * NC + ch];
  const int hoff = offT[ch * 16 + e];

  const int sr = lane >> 2;                          // row within subtile
  const int sc = (((lane & 3) - (sr >> 1)) & 3) * 8; // swizzled source k-chunk
  const int i0 = bm * 128 + w * 32 + sr;
  const int i1 = i0 + 16;
  const int r0 = rl[i0 < cnt_ec ? i0 : cnt_ec - 1];
  const int r1 = rl[i1 < cnt_ec ? i1 : cnt_ec - 1];
  const unsigned short* gA0 = xb + (size_t)r0 * 1024 + sc;
  const unsigned short* gA1 = xb + (size_t)r1 * 1024 + sc;
  const unsigned short* Bb = Bt + (size_t)e * 1024 * 1024 + (size_t)bn * 128 * 1024;
  const unsigned short* gB0 = Bb + (size_t)(w * 32 + sr) * 1024 + sc;
  const unsigned short* gB1 = gB0 + (size_t)16 * 1024;
  unsigned short* lA0 = &As[(w * 2) * 512];
  unsigned short* lA1 = &As[(w * 2 + 1) * 512];
  unsigned short* lB0 = &Bs[(w * 2) * 512];
  unsigned short* lB1 = &Bs[(w * 2 + 1) * 512];

  f32x4 acc[4][4] = {};
  const int frow = lane & 15;
  const int rcA = (((lane >> 4) + (frow >> 1)) & 3) * 8;

  for (int k0 = 0; k0 < 1024; k0 += 32) {
    __syncthreads();
    gl_lds16(gA0 + k0, lA0);
    gl_lds16(gA1 + k0, lA1);
    gl_lds16(gB0 + k0, lB0);
    gl_lds16(gB1 + k0, lB1);
    __syncthreads();
    bf16x8 af[4], bfr[4];
#pragma unroll
    for (int mt = 0; mt < 4; ++mt)
      af[mt] = *(const bf16x8*)&As[(wm * 4 + mt) * 512 + frow * 32 + rcA];
#pragma unroll
    for (int nt = 0; nt < 4; ++nt)
      bfr[nt] = *(const bf16x8*)&Bs[(wn * 4 + nt) * 512 + frow * 32 + rcA];
#pragma unroll
    for (int mt = 0; mt < 4; ++mt)
#pragma unroll
      for (int nt = 0; nt < 4; ++nt)
        acc[mt][nt] = __builtin_amdgcn_mfma_f32_16x16x32_bf16(
            af[mt], bfr[nt], acc[mt][nt], 0, 0, 0);
  }

  const int crow = (lane >> 4) * 4;
  const int ccol = lane & 15;
  const float* brow = bias + (size_t)e * 1024 + (size_t)bn * 128;
#pragma unroll
  for (int nt = 0; nt < 4; ++nt) {
    int col = wn * 64 + nt * 16 + ccol;
    float bv = brow[col];
#pragma unroll
    for (int mt = 0; mt < 4; ++mt) {
      f32x4 v = acc[mt][nt];
#pragma unroll
      for (int r = 0; r < 4; ++r) {
        int rowl = bm * 128 + wm * 64 + mt * 16 + crow + r;
        if (rowl < cnt_ec) {   // compact slots are shared: guard pad rows
          float val = fmaxf(v[r] + bv, 0.f);
          h[(size_t)(hoff + rowl) * 1024 + bn * 128 + col] = f2bf(val);
        }
      }
    }
  }
}

// ---------- FC2: eo[off+i][:] = h[off+i] @ We2[e] + be2[e], compact ----------
__global__ __launch_bounds__(256) void gemm_fc2(
    const unsigned short* __restrict__ h,             // compact [cap][1024]
    const unsigned short* __restrict__ Bt,            // We2t [16][512][1024]
    unsigned short* __restrict__ eo,                  // compact [cap][512]
    const float* __restrict__ bias,                   // be2 [16][512]
    const int* __restrict__ cnt, const int* __restrict__ offT,
    int ch, int NC) {
  __shared__ __align__(16) unsigned short As[8 * 512];
  __shared__ __align__(16) unsigned short Bs[8 * 512];
  const int e = blockIdx.z;
  const int cnt_ec = cnt[e * NC + ch];
  const int bm = blockIdx.x, bn = blockIdx.y;
  if (bm * 128 >= cnt_ec) return;
  const int tid = threadIdx.x;
  const int w = tid >> 6, lane = tid & 63;
  const int wm = w >> 1, wn = w & 1;
  const int base = offT[ch * 16 + e];

  const int sr = lane >> 2;
  const int sc = (((lane & 3) - (sr >> 1)) & 3) * 8;
  // contiguous compact rows; reads past cnt_ec hit neighbor slots (finite) and
  // their results are discarded by the epilogue guard
  const unsigned short* Ab = h + (size_t)(base + bm * 128) * 1024;
  const unsigned short* gA0 = Ab + (size_t)(w * 32 + sr) * 1024 + sc;
  const unsigned short* gA1 = gA0 + (size_t)16 * 1024;
  const unsigned short* Bb = Bt + (size_t)e * 512 * 1024 + (size_t)bn * 128 * 1024;
  const unsigned short* gB0 = Bb + (size_t)(w * 32 + sr) * 1024 + sc;
  const unsigned short* gB1 = gB0 + (size_t)16 * 1024;
  unsigned short* lA0 = &As[(w * 2) * 512];
  unsigned short* lA1 = &As[(w * 2 + 1) * 512];
  unsigned short* lB0 = &Bs[(w * 2) * 512];
  unsigned short* lB1 = &Bs[(w * 2 + 1) * 512];

  f32x4 acc[4][4] = {};
  const int frow = lane & 15;
  const int rcA = (((lane >> 4) + (frow >> 1)) & 3) * 8;

  for (int k0 = 0; k0 < 1024; k0 += 32) {
    __syncthreads();
    gl_lds16(gA0 + k0, lA0);
    gl_lds16(gA1 + k0, lA1);
    gl_lds16(gB0 + k0, lB0);
    gl_lds16(gB1 + k0, lB1);
    __syncthreads();
    bf16x8 af[4], bfr[4];
#pragma unroll
    for (int mt = 0; mt < 4; ++mt)
      af[mt] = *(const bf16x8*)&As[(wm * 4 + mt) * 512 + frow * 32 + rcA];
#pragma unroll
    for (int nt = 0; nt < 4; ++nt)
      bfr[nt] = *(const bf16x8*)&Bs[(wn * 4 + nt) * 512 + frow * 32 + rcA];
#pragma unroll
    for (int mt = 0; mt < 4; ++mt)
#pragma unroll
      for (int nt = 0; nt < 4; ++nt)
        acc[mt][nt] = __builtin_amdgcn_mfma_f32_16x16x32_bf16(
            af[mt], bfr[nt], acc[mt][nt], 0, 0, 0);
  }

  const int crow = (lane >> 4) * 4;
  const int ccol = lane & 15;
  const float* brow = bias + (size_t)e * 512 + (size_t)bn * 128;
#pragma unroll
  for (int nt = 0; nt < 4; ++nt) {
    int col = wn * 64 + nt * 16 + ccol;
    float bv = brow[col];
#pragma unroll
    for (int mt = 0; mt < 4; ++mt) {
      f32x4 v = acc[mt][nt];
#pragma unroll
      for (int r = 0; r < 4; ++r) {
        int rowl = bm * 128 + wm * 64 + mt * 16 + crow + r;
        if (rowl < cnt_ec)
          eo[(size_t)(base + rowl) * 512 + bn * 128 + col] = f2bf(v[r] + bv);
      }
    }
  }
}

// ---------- dense bf16 MFMA GEMM (towers): C = A @ Bt^T + bias, opt relu ----------
template <bool RELU, bool OUT_BF16>
__global__ __launch_bounds__(256) void gemm_bt(
    const unsigned short* __restrict__ A, int lda, long long strideA,
    const unsigned short* __restrict__ Bt, int ldb, long long strideB,
    void* __restrict__ Cv, int ldc, long long strideC,
    const float* __restrict__ bias, int strideBias, int K) {
  __shared__ __align__(16) unsigned short As[8 * 512];
  __shared__ __align__(16) unsigned short Bs[8 * 512];
  const int tid = threadIdx.x;
  const int w = tid >> 6, lane = tid & 63;
  const int wm = w >> 1, wn = w & 1;
  const int bm = blockIdx.x, bn = blockIdx.y, bz = blockIdx.z;

  const unsigned short* Ab = A + (size_t)bz * strideA + (size_t)bm * 128 * lda;
  const unsigned short* Bb = Bt + (size_t)bz * strideB + (size_t)bn * 128 * ldb;

  const int sr = lane >> 2;
  const int sc = (((lane & 3) - (sr >> 1)) & 3) * 8;
  const unsigned short* gA0 = Ab + (size_t)(w * 32 + sr) * lda + sc;
  const unsigned short* gA1 = gA0 + (size_t)16 * lda;
  const unsigned short* gB0 = Bb + (size_t)(w * 32 + sr) * ldb + sc;
  const unsigned short* gB1 = gB0 + (size_t)16 * ldb;
  unsigned short* lA0 = &As[(w * 2) * 512];
  unsigned short* lA1 = &As[(w * 2 + 1) * 512];
  unsigned short* lB0 = &Bs[(w * 2) * 512];
  unsigned short* lB1 = &Bs[(w * 2 + 1) * 512];

  f32x4 acc[4][4] = {};
  const int frow = lane & 15;
  const int rcA = (((lane >> 4) + (frow >> 1)) & 3) * 8;

  for (int k0 = 0; k0 < K; k0 += 32) {
    __syncthreads();
    gl_lds16(gA0 + k0, lA0);
    gl_lds16(gA1 + k0, lA1);
    gl_lds16(gB0 + k0, lB0);
    gl_lds16(gB1 + k0, lB1);
    __syncthreads();
    bf16x8 af[4], bfr[4];
#pragma unroll
    for (int mt = 0; mt < 4; ++mt)
      af[mt] = *(const bf16x8*)&As[(wm * 4 + mt) * 512 + frow * 32 + rcA];
#pragma unroll
    for (int nt = 0; nt < 4; ++nt)
      bfr[nt] = *(const bf16x8*)&Bs[(wn * 4 + nt) * 512 + frow * 32 + rcA];
#pragma unroll
    for (int mt = 0; mt < 4; ++mt)
#pragma unroll
      for (int nt = 0; nt < 4; ++nt)
        acc[mt][nt] = __builtin_amdgcn_mfma_f32_16x16x32_bf16(
            af[mt], bfr[nt], acc[mt][nt], 0, 0, 0);
  }

  const int crow = (lane >> 4) * 4;
  const int ccol = lane & 15;
  const float* brow = bias + (size_t)bz * strideBias + (size_t)bn * 128;
#pragma unroll
  for (int nt = 0; nt < 4; ++nt) {
    int col = wn * 64 + nt * 16 + ccol;
    float bv = brow[col];
#pragma unroll
    for (int mt = 0; mt < 4; ++mt) {
      f32x4 v = acc[mt][nt];
#pragma unroll
      for (int r = 0; r < 4; ++r) {
        float val = v[r] + bv;
        if (RELU) val = fmaxf(val, 0.f);
        size_t row = (size_t)bm * 128 + wm * 64 + mt * 16 + crow + r;
        size_t off = (size_t)bz * strideC + row * ldc + (size_t)bn * 128 + col;
        if (OUT_BF16) ((unsigned short*)Cv)[off] = f2bf(val);
        else          ((float*)Cv)[off] = val;
      }
    }
  }
}

// ---------- combine: go[t][b][:] = sum_{e: g>0} g * eo[slot(e,b)][:] ----------
__global__ __launch_bounds__(128) void combine_kernel(
    const unsigned short* __restrict__ eo, const float* __restrict__ g,
    unsigned short* __restrict__ go, const int* __restrict__ pos,
    const int* __restrict__ startT, const int* __restrict__ offT,
    int ch, int chunk_rows, int NC) {
  const int bl = blockIdx.x, t = blockIdx.y;
  const int b = ch * chunk_rows + bl;
  const int o = threadIdx.x;
  const float* grow = g + ((size_t)t * 8192 + b) * 16;
  float a0 = 0, a1 = 0, a2 = 0, a3 = 0;
  for (int e = 0; e < 16; ++e) {
    float ge = grow[e];
    if (ge > 0.f) {
      int i = pos[e * 8192 + b] - startT[e * NC + ch];
      const unsigned short* row = eo + ((size_t)(offT[ch * 16 + e] + i)) * 512;
      a0 = fmaf(ge, bf2f(row[o]), a0);
      a1 = fmaf(ge, bf2f(row[o + 128]), a1);
      a2 = fmaf(ge, bf2f(row[o + 256]), a2);
      a3 = fmaf(ge, bf2f(row[o + 384]), a3);
    }
  }
  unsigned short* orow = go + ((size_t)t * 8192 + b) * 512;
  orow[o] = f2bf(a0); orow[o + 128] = f2bf(a1);
  orow[o + 256] = f2bf(a2); orow[o + 384] = f2bf(a3);
}

// ---------- final: out[t*8192+b] = dot(t2[t][b][:256], Wh3[t]) + bh3[t] ----------
__global__ __launch_bounds__(256) void final_dot(const float* __restrict__ t2,
                                                 const float* __restrict__ Wh3,
                                                 const float* __restrict__ bh3,
                                                 float* __restrict__ out) {
  const int row = blockIdx.x * 4 + (threadIdx.x >> 6);  // one wave per row
  const int lane = threadIdx.x & 63;
  const int t = row >> 13;
  const float* trow = t2 + (size_t)row * 256;
  const float* w = Wh3 + t * 256;
  float s = 0.f;
#pragma unroll
  for (int j = 0; j < 4; ++j) s = fmaf(trow[lane + j * 64], w[lane + j * 64], s);
#pragma unroll
  for (int off = 32; off > 0; off >>= 1) s += __shfl_down(s, off, 64);
  if (lane == 0) out[row] = s + bh3[t];
}

// ---------- orchestration ----------
extern "C" void kernel_launch(void* const* d_in, const int* in_sizes, int n_in,
                              void* d_out, int out_size, void* d_ws, size_t ws_size,
                              hipStream_t stream) {
  (void)in_sizes; (void)n_in; (void)out_size;
  const float* x   = (const float*)d_in[0];
  const float* We1 = (const float*)d_in[1];
  const float* be1 = (const float*)d_in[2];
  const float* We2 = (const float*)d_in[3];
  const float* be2 = (const float*)d_in[4];
  const float* Wg  = (const float*)d_in[5];
  const float* Wn  = (const float*)d_in[6];
  const float* Wh1 = (const float*)d_in[7];
  const float* bh1 = (const float*)d_in[8];
  const float* Wh2 = (const float*)d_in[9];
  const float* bh2 = (const float*)d_in[10];
  const float* Wh3 = (const float*)d_in[11];
  const float* bh3 = (const float*)d_in[12];

  auto al = [](size_t v) { return (v + 255) & ~(size_t)255; };
  const size_t sz_xb   = al((size_t)8192 * 1024 * 2);
  const size_t sz_We1t = al((size_t)16 * 1024 * 1024 * 2);
  const size_t sz_We2t = al((size_t)16 * 512 * 1024 * 2);
  const size_t sz_Wh1t = al((size_t)2 * 512 * 512 * 2);
  const size_t sz_Wh2t = al((size_t)2 * 256 * 512 * 2);
  const size_t sz_g    = al((size_t)2 * 8192 * 16 * 4);
  const size_t sz_go   = al((size_t)2 * 8192 * 512 * 2);
  const size_t sz_rl   = al((size_t)16 * 8192 * 4);
  const size_t sz_pos  = al((size_t)16 * 8192 * 4);
  const size_t sz_tab  = al((size_t)16 * 8 * 4);   // cnt/startT/offT each (NC<=8)
  const size_t fixed = sz_xb + sz_We1t + sz_We2t + sz_Wh1t + sz_Wh2t +
                       sz_g + sz_go + sz_rl + sz_pos + 3 * sz_tab;
  const size_t sz_t1 = al((size_t)2 * 8192 * 512 * 2);
  const size_t sz_t2 = al((size_t)2 * 8192 * 256 * 4);
  const size_t sz_t12 = sz_t1 + sz_t2;

  // choose fewest chunks whose compact region fits.
  // cap per chunk = chunk_rows * 8 slots (<=8 distinct experts per row, hard bound)
  int NC = 8;
  for (int cand = 1; cand <= 8; cand <<= 1) {
    int chunk_rows = 8192 / cand;
    size_t cap = (size_t)chunk_rows * 8;
    size_t region = al(cap * 1024 * 2) + al(cap * 512 * 2) + (1u << 19);
    if (region < sz_t12) region = sz_t12;
    if (fixed + region <= ws_size) { NC = cand; break; }
  }
  const int chunk_rows = 8192 / NC;
  const size_t cap = (size_t)chunk_rows * 8;
  const size_t sz_h = al(cap * 1024 * 2);

  char* ws = (char*)d_ws;
  size_t off = 0;
  auto carve = [&](size_t bytes) -> char* { char* p = ws + off; off += bytes; return p; };
  unsigned short* xb   = (unsigned short*)carve(sz_xb);
  unsigned short* We1t = (unsigned short*)carve(sz_We1t);
  unsigned short* We2t = (unsigned short*)carve(sz_We2t);
  unsigned short* Wh1t = (unsigned short*)carve(sz_Wh1t);
  unsigned short* Wh2t = (unsigned short*)carve(sz_Wh2t);
  float* g             = (float*)carve(sz_g);
  unsigned short* go   = (unsigned short*)carve(sz_go);
  int* rowlist         = (int*)carve(sz_rl);
  int* pos             = (int*)carve(sz_pos);
  int* cnt             = (int*)carve(sz_tab);
  int* startT          = (int*)carve(sz_tab);
  int* offT            = (int*)carve(sz_tab);
  char* region         = ws + off;
  unsigned short* h    = (unsigned short*)region;            // compact [cap][1024]
  unsigned short* eo   = (unsigned short*)(region + sz_h);   // compact [cap][512]
  unsigned short* t1   = (unsigned short*)region;            // aliases (h dead)
  float* t2            = (float*)(region + sz_t1);

  // prep: casts + weight transposes (B operands need N x K)
  cvt_x<<<8192, 256, 0, stream>>>(x, xb);
  transpose_bf16<<<dim3(32, 32, 16), 256, 0, stream>>>(We1, We1t, 1024, 1024);
  transpose_bf16<<<dim3(16, 32, 16), 256, 0, stream>>>(We2, We2t, 1024, 512);
  transpose_bf16<<<dim3(16, 16, 2), 256, 0, stream>>>(Wh1, Wh1t, 512, 512);
  transpose_bf16<<<dim3(8, 16, 2), 256, 0, stream>>>(Wh2, Wh2t, 512, 256);

  // gating + global sorted routing (no memsets needed: routing writes all cnt)
  gating_kernel<<<1024, 256, 0, stream>>>(x, Wg, Wn, g);
  routing_scan<<<16, 256, 0, stream>>>(g, cnt, rowlist, pos, NC);
  make_tables<<<1, 64, 0, stream>>>(cnt, startT, offT, NC);

  // sparse expert pipeline over NC compact chunks
  const int bmW = chunk_rows / 128;   // worst-case row-blocks per expert
  for (int ch = 0; ch < NC; ++ch) {
    gemm_fc1<<<dim3(bmW, 8, 16), 256, 0, stream>>>(
        xb, We1t, h, be1, rowlist, cnt, startT, offT, ch, NC);
    gemm_fc2<<<dim3(bmW, 4, 16), 256, 0, stream>>>(
        h, We2t, eo, be2, cnt, offT, ch, NC);
    combine_kernel<<<dim3(chunk_rows, 2), 128, 0, stream>>>(
        eo, g, go, pos, startT, offT, ch, chunk_rows, NC);
  }

  // towers (dense, full batch)
  gemm_bt<true, true><<<dim3(64, 4, 2), 256, 0, stream>>>(
      go, 512, (long long)8192 * 512, Wh1t, 512, (long long)512 * 512,
      t1, 512, (long long)8192 * 512, bh1, 512, 512);
  gemm_bt<true, false><<<dim3(64, 2, 2), 256, 0, stream>>>(
      t1, 512, (long long)8192 * 512, Wh2t, 512, (long long)256 * 512,
      t2, 256, (long long)8192 * 256, bh2, 256, 512);

  final_dot<<<4096, 256, 0, stream>>>(t2, Wh3, bh3, (float*)d_out);
}